// Round 1
// baseline (2078.792 us; speedup 1.0000x reference)
//
#include <hip/hip_runtime.h>

constexpr int HD = 128;  // hidden size

// ---------------------------------------------------------------------------
// Kernel A: per-row reciprocal L1 norm of x.  One wave (64 lanes) per row,
// each lane loads a float2 (8B/lane, coalesced 512B per row).
// ---------------------------------------------------------------------------
__global__ void rnorm_kernel(const float* __restrict__ x,
                             float* __restrict__ rnorm, int N) {
    int wave = (blockIdx.x * blockDim.x + threadIdx.x) >> 6;
    int lane = threadIdx.x & 63;
    if (wave >= N) return;
    float2 v = *((const float2*)(x + (size_t)wave * HD) + lane);
    float s = fabsf(v.x) + fabsf(v.y);
#pragma unroll
    for (int m = 1; m < 64; m <<= 1) s += __shfl_xor(s, m, 64);
    if (lane == 0) rnorm[wave] = 1.0f / fmaxf(s, 1e-12f);
}

// ---------------------------------------------------------------------------
// Kernel T: transpose W (H x H) into Wt in global scratch so the GEMM kernel
// can stage it into LDS with linear, conflict-free, coalesced copies.
// Wt[k*H + h] = W[h*H + k]
// ---------------------------------------------------------------------------
__global__ void wt_kernel(const float* __restrict__ W, float* __restrict__ Wt) {
    int t = blockIdx.x * blockDim.x + threadIdx.x;  // 0 .. H*H-1
    int h = t >> 7, k = t & (HD - 1);
    Wt[k * HD + h] = W[t];
}

// ---------------------------------------------------------------------------
// Kernel B: COO SpMM with atomic scatter-add.
// One wave per edge (grid-stride): gather the 512B source row of x, scale by
// A_vals[e] * rnorm[col] (i.e. the row-normalized xn), atomicAdd into f[row].
// ---------------------------------------------------------------------------
__global__ void spmm_kernel(const float* __restrict__ x,
                            const int* __restrict__ rows,
                            const int* __restrict__ cols,
                            const float* __restrict__ vals,
                            const float* __restrict__ rnorm,
                            float* __restrict__ f, int E) {
    int lane = threadIdx.x & 63;
    int gw = (blockIdx.x * blockDim.x + threadIdx.x) >> 6;
    int nw = (gridDim.x * blockDim.x) >> 6;
    for (int e = gw; e < E; e += nw) {
        int r = rows[e];
        int c = cols[e];
        float scale = vals[e] * rnorm[c];
        float2 v = *((const float2*)(x + (size_t)c * HD) + lane);
        float* dst = f + (size_t)r * HD + 2 * lane;
        atomicAdd(dst, v.x * scale);
        atomicAdd(dst + 1, v.y * scale);
    }
}

// ---------------------------------------------------------------------------
// Kernel C: g = f @ W^T + b ; row L1-normalize ; relu ; out = x + ts * g.
// One wave per row, lane owns output columns (2*lane, 2*lane+1).
// W^T lives in LDS (64 KiB); f-row broadcast via v_readlane (no LDS traffic).
// Writes in-place over f (d_out) — safe: the wave fully reads its f-row
// before writing, and rows are partitioned across waves.
// ---------------------------------------------------------------------------
__global__ void gemm_epi_kernel(const float* __restrict__ x,
                                const float* __restrict__ Wt,
                                const float* __restrict__ b,
                                const float* __restrict__ ts_p,
                                float* __restrict__ f, int N) {
    __shared__ float lds[HD * HD];  // 64 KiB, Wt layout [k][h]
    {
        const float4* src4 = (const float4*)Wt;
        float4* dst4 = (float4*)lds;
        for (int i = threadIdx.x; i < HD * HD / 4; i += blockDim.x)
            dst4[i] = src4[i];
    }
    __syncthreads();

    int lane = threadIdx.x & 63;
    int wave = threadIdx.x >> 6;
    float ts = ts_p[0];
    float b0 = b[2 * lane], b1 = b[2 * lane + 1];
    int stride = gridDim.x * 4;

    for (int row = blockIdx.x * 4 + wave; row < N; row += stride) {
        float2 fv = *((const float2*)(f + (size_t)row * HD) + lane);
        float acc0 = 0.f, acc1 = 0.f;
#pragma unroll
        for (int j = 0; j < 64; ++j) {
            float fk0 = __uint_as_float(
                __builtin_amdgcn_readlane(__float_as_uint(fv.x), j));
            float fk1 = __uint_as_float(
                __builtin_amdgcn_readlane(__float_as_uint(fv.y), j));
            float2 w0 = *((const float2*)(lds + (2 * j) * HD) + lane);
            float2 w1 = *((const float2*)(lds + (2 * j + 1) * HD) + lane);
            acc0 = fmaf(fk0, w0.x, acc0);
            acc0 = fmaf(fk1, w1.x, acc0);
            acc1 = fmaf(fk0, w0.y, acc1);
            acc1 = fmaf(fk1, w1.y, acc1);
        }
        float g0 = acc0 + b0, g1 = acc1 + b1;
        float s = fabsf(g0) + fabsf(g1);
#pragma unroll
        for (int m = 1; m < 64; m <<= 1) s += __shfl_xor(s, m, 64);
        float rn = 1.0f / fmaxf(s, 1e-12f);
        g0 = fmaxf(g0 * rn, 0.f);
        g1 = fmaxf(g1 * rn, 0.f);
        float2 xv = *((const float2*)(x + (size_t)row * HD) + lane);
        float2 o;
        o.x = xv.x + ts * g0;
        o.y = xv.y + ts * g1;
        *((float2*)(f + (size_t)row * HD) + lane) = o;
    }
}

extern "C" void kernel_launch(void* const* d_in, const int* in_sizes, int n_in,
                              void* d_out, int out_size, void* d_ws,
                              size_t ws_size, hipStream_t stream) {
    const float* x = (const float*)d_in[0];
    const int* Ar = (const int*)d_in[1];
    const int* Ac = (const int*)d_in[2];
    const float* Av = (const float*)d_in[3];
    const float* W = (const float*)d_in[4];
    const float* b = (const float*)d_in[5];
    const float* ts = (const float*)d_in[6];

    int N = in_sizes[0] / HD;
    int E = in_sizes[1];

    float* f = (float*)d_out;          // accumulator, then final output (in-place)
    float* rnorm = (float*)d_ws;       // N floats
    int wt_off = ((N + 255) >> 8) << 8;
    float* Wt = (float*)d_ws + wt_off; // H*H floats

    // zero the scatter-add accumulator (graph-capturable async memset)
    hipMemsetAsync(d_out, 0, (size_t)N * HD * sizeof(float), stream);

    // A: reciprocal row L1 norms
    int ablocks = (N + 3) / 4;
    rnorm_kernel<<<ablocks, 256, 0, stream>>>(x, rnorm, N);

    // T: transpose W -> Wt
    wt_kernel<<<HD * HD / 256, 256, 0, stream>>>(W, Wt);

    // B: SpMM scatter-add
    spmm_kernel<<<2048, 256, 0, stream>>>(x, Ar, Ac, Av, rnorm, f, E);

    // C: GEMM + bias + normalize + relu + residual (in-place on d_out)
    gemm_epi_kernel<<<512, 256, 0, stream>>>(x, Wt, b, ts, f, N);
}

// Round 2
// 452.320 us; speedup vs baseline: 4.5958x; 4.5958x over previous
//
#include <hip/hip_runtime.h>

constexpr int HD = 128;  // hidden size

// ---------------------------------------------------------------------------
// rnorm: per-row reciprocal L1 norm of x. One wave per row.
// ---------------------------------------------------------------------------
__global__ void rnorm_kernel(const float* __restrict__ x,
                             float* __restrict__ rnorm, int N) {
    int wave = (blockIdx.x * blockDim.x + threadIdx.x) >> 6;
    int lane = threadIdx.x & 63;
    if (wave >= N) return;
    float2 v = *((const float2*)(x + (size_t)wave * HD) + lane);
    float s = fabsf(v.x) + fabsf(v.y);
#pragma unroll
    for (int m = 1; m < 64; m <<= 1) s += __shfl_xor(s, m, 64);
    if (lane == 0) rnorm[wave] = 1.0f / fmaxf(s, 1e-12f);
}

// ---------------------------------------------------------------------------
// Wp pair-interleaved layout for the GEMM LDS tile:
//   Wp[k2*256 + 2*h + j] = W[h][2*k2 + j]   (k2 in [0,64), h in [0,128), j in {0,1})
// Lets the GEMM inner loop read one contiguous float4 per lane (conflict-free
// ds_read_b128): lane gets (W[2l][2k2], W[2l][2k2+1], W[2l+1][2k2], W[2l+1][2k2+1]).
// ---------------------------------------------------------------------------
__global__ void wp_kernel(const float* __restrict__ W, float* __restrict__ Wp) {
    int t = blockIdx.x * blockDim.x + threadIdx.x;  // 0 .. 16383
    int k2 = t >> 8, rem = t & 255, h = rem >> 1, j = rem & 1;
    Wp[t] = W[h * HD + 2 * k2 + j];
}

// ---------------------------------------------------------------------------
// CSR construction: histogram -> 2-level exclusive scan -> scatter permute.
// ---------------------------------------------------------------------------
__global__ void hist_kernel(const int* __restrict__ rows,
                            int* __restrict__ counts, int E) {
    int e = blockIdx.x * blockDim.x + threadIdx.x;
    if (e < E) atomicAdd(&counts[rows[e]], 1);
}

// block-local exclusive scan of 1024 counts per block (256 thr x 4 each)
__global__ void scan1_kernel(const int* __restrict__ counts,
                             int* __restrict__ rowptr,
                             int* __restrict__ bsums, int N) {
    __shared__ int lds[256];
    int t = threadIdx.x;
    int base = blockIdx.x * 1024;
    int v[4];
    int s = 0;
#pragma unroll
    for (int i = 0; i < 4; ++i) {
        int idx = base + t * 4 + i;
        v[i] = (idx < N) ? counts[idx] : 0;
        s += v[i];
    }
    lds[t] = s;
    __syncthreads();
    for (int off = 1; off < 256; off <<= 1) {
        int add = (t >= off) ? lds[t - off] : 0;
        __syncthreads();
        lds[t] += add;
        __syncthreads();
    }
    int run = lds[t] - s;  // exclusive prefix for this thread's 4 elements
#pragma unroll
    for (int i = 0; i < 4; ++i) {
        int idx = base + t * 4 + i;
        if (idx < N) rowptr[idx] = run;
        run += v[i];
    }
    if (t == 255) bsums[blockIdx.x] = lds[255];
}

// single-block exclusive scan of the block sums (nb <= 1024)
__global__ void scan2_kernel(int* __restrict__ bsums, int nb) {
    __shared__ int lds[256];
    int t = threadIdx.x;
    int v[4];
    int s = 0;
#pragma unroll
    for (int i = 0; i < 4; ++i) {
        int idx = t * 4 + i;
        v[i] = (idx < nb) ? bsums[idx] : 0;
        s += v[i];
    }
    lds[t] = s;
    __syncthreads();
    for (int off = 1; off < 256; off <<= 1) {
        int add = (t >= off) ? lds[t - off] : 0;
        __syncthreads();
        lds[t] += add;
        __syncthreads();
    }
    int run = lds[t] - s;
#pragma unroll
    for (int i = 0; i < 4; ++i) {
        int idx = t * 4 + i;
        if (idx < nb) {
            int tmp = v[i];
            bsums[idx] = run;
            run += tmp;
        }
    }
}

__global__ void scan3_kernel(int* __restrict__ rowptr, int* __restrict__ cursor,
                             const int* __restrict__ bsums, int N) {
    int i = blockIdx.x * blockDim.x + threadIdx.x;
    if (i >= N) return;
    int v = rowptr[i] + bsums[i >> 10];
    rowptr[i] = v;
    cursor[i] = v;
}

// permute edges into CSR order; pre-scale edge value by rnorm of source col
__global__ void scatter_kernel(const int* __restrict__ rows,
                               const int* __restrict__ cols,
                               const float* __restrict__ vals,
                               const float* __restrict__ rnorm,
                               int* __restrict__ cursor,
                               int* __restrict__ ecol, float* __restrict__ eval,
                               int E) {
    int e = blockIdx.x * blockDim.x + threadIdx.x;
    if (e >= E) return;
    int r = rows[e], c = cols[e];
    int p = atomicAdd(&cursor[r], 1);
    ecol[p] = c;
    eval[p] = vals[e] * rnorm[c];
}

// ---------------------------------------------------------------------------
// Fused CSR-SpMM + GEMM + epilogue. One wave handles 4 consecutive rows:
//  - accumulate each f-row in registers from gathered x rows (no atomics)
//  - g = f @ W^T + b via LDS-staged Wp (one ds_read_b128 per 2 k's, reused 4x)
//  - L1-normalize, relu, out = x + ts * g  (single write per row)
// ---------------------------------------------------------------------------
__global__ void __launch_bounds__(1024) spmm_gemm_kernel(
    const float* __restrict__ x, const int* __restrict__ rowptr,
    const int* __restrict__ counts, const int* __restrict__ ecol,
    const float* __restrict__ eval, const float* __restrict__ Wp,
    const float* __restrict__ b, const float* __restrict__ tsp,
    float* __restrict__ out, int N) {
    __shared__ float lds[HD * HD];  // 64 KiB
    {
        const float4* s4 = (const float4*)Wp;
        float4* d4 = (float4*)lds;
        for (int i = threadIdx.x; i < HD * HD / 4; i += blockDim.x) d4[i] = s4[i];
    }
    __syncthreads();

    int lane = threadIdx.x & 63;
    int wid = threadIdx.x >> 6;
    float ts = tsp[0];
    float b0 = b[2 * lane], b1 = b[2 * lane + 1];

    int r0 = (blockIdx.x * (blockDim.x >> 6) + wid) * 4;
    if (r0 >= N) return;  // no barriers after this point

    // ---- gather phase: f rows r0..r0+3 into registers ----
    float a0[4] = {0.f, 0.f, 0.f, 0.f}, a1[4] = {0.f, 0.f, 0.f, 0.f};
#pragma unroll
    for (int rr = 0; rr < 4; ++rr) {
        int row = r0 + rr;
        if (row >= N) break;
        int beg = rowptr[row], cnt = counts[row];
        float x0 = 0.f, y0 = 0.f, x1 = 0.f, y1 = 0.f;
        int j = 0;
        for (; j + 2 <= cnt; j += 2) {
            int c0 = ecol[beg + j], c1 = ecol[beg + j + 1];
            float s0 = eval[beg + j], s1 = eval[beg + j + 1];
            float2 v0 = *((const float2*)(x + (size_t)c0 * HD) + lane);
            float2 v1 = *((const float2*)(x + (size_t)c1 * HD) + lane);
            x0 = fmaf(v0.x, s0, x0);
            y0 = fmaf(v0.y, s0, y0);
            x1 = fmaf(v1.x, s1, x1);
            y1 = fmaf(v1.y, s1, y1);
        }
        if (j < cnt) {
            int c0 = ecol[beg + j];
            float s0 = eval[beg + j];
            float2 v0 = *((const float2*)(x + (size_t)c0 * HD) + lane);
            x0 = fmaf(v0.x, s0, x0);
            y0 = fmaf(v0.y, s0, y0);
        }
        a0[rr] = x0 + x1;
        a1[rr] = y0 + y1;
    }

    // ---- GEMM phase: g[c] = dot(f, W[c,:]) for c = 2*lane, 2*lane+1 ----
    float g0[4] = {0.f, 0.f, 0.f, 0.f}, g1[4] = {0.f, 0.f, 0.f, 0.f};
#pragma unroll 8
    for (int k2 = 0; k2 < 64; ++k2) {
        float4 w = *((const float4*)(lds + k2 * 256) + lane);
#pragma unroll
        for (int rr = 0; rr < 4; ++rr) {
            float fk0 = __uint_as_float(
                __builtin_amdgcn_readlane(__float_as_uint(a0[rr]), k2));
            float fk1 = __uint_as_float(
                __builtin_amdgcn_readlane(__float_as_uint(a1[rr]), k2));
            g0[rr] = fmaf(fk0, w.x, g0[rr]);
            g0[rr] = fmaf(fk1, w.y, g0[rr]);
            g1[rr] = fmaf(fk0, w.z, g1[rr]);
            g1[rr] = fmaf(fk1, w.w, g1[rr]);
        }
    }

    // ---- epilogue: bias, L1 normalize, relu, residual ----
#pragma unroll
    for (int rr = 0; rr < 4; ++rr) {
        int row = r0 + rr;
        if (row >= N) break;
        float G0 = g0[rr] + b0, G1 = g1[rr] + b1;
        float s = fabsf(G0) + fabsf(G1);
#pragma unroll
        for (int m = 1; m < 64; m <<= 1) s += __shfl_xor(s, m, 64);
        float rn = 1.0f / fmaxf(s, 1e-12f);
        G0 = fmaxf(G0 * rn, 0.f);
        G1 = fmaxf(G1 * rn, 0.f);
        float2 xv = *((const float2*)(x + (size_t)row * HD) + lane);
        float2 o;
        o.x = fmaf(ts, G0, xv.x);
        o.y = fmaf(ts, G1, xv.y);
        *((float2*)(out + (size_t)row * HD) + lane) = o;
    }
}

extern "C" void kernel_launch(void* const* d_in, const int* in_sizes, int n_in,
                              void* d_out, int out_size, void* d_ws,
                              size_t ws_size, hipStream_t stream) {
    const float* x = (const float*)d_in[0];
    const int* Ar = (const int*)d_in[1];
    const int* Ac = (const int*)d_in[2];
    const float* Av = (const float*)d_in[3];
    const float* W = (const float*)d_in[4];
    const float* b = (const float*)d_in[5];
    const float* ts = (const float*)d_in[6];

    int N = in_sizes[0] / HD;
    int E = in_sizes[1];

    float* out = (float*)d_out;

    char* ws = (char*)d_ws;
    size_t o = 0;
    auto take = [&](size_t bytes) {
        void* p = ws + o;
        o += (bytes + 511) & ~(size_t)511;
        return p;
    };
    float* rnorm = (float*)take((size_t)N * 4);
    int* counts = (int*)take((size_t)N * 4);
    int* rowptr = (int*)take((size_t)N * 4);
    int* cursor = (int*)take((size_t)N * 4);
    int nb = (N + 1023) / 1024;
    int* bsums = (int*)take((size_t)nb * 4);
    float* Wp = (float*)take((size_t)HD * HD * 4);
    int* ecol = (int*)take((size_t)E * 4);
    float* eval = (float*)take((size_t)E * 4);
    // total ws use: ~4*N*4 + 64KB + 2*E*4 ~= 14.5 MB

    hipMemsetAsync(counts, 0, (size_t)N * 4, stream);
    rnorm_kernel<<<(N + 3) / 4, 256, 0, stream>>>(x, rnorm, N);
    wp_kernel<<<HD * HD / 256, 256, 0, stream>>>(W, Wp);
    hist_kernel<<<(E + 255) / 256, 256, 0, stream>>>(Ar, counts, E);
    scan1_kernel<<<nb, 256, 0, stream>>>(counts, rowptr, bsums, N);
    scan2_kernel<<<1, 256, 0, stream>>>(bsums, nb);
    scan3_kernel<<<(N + 255) / 256, 256, 0, stream>>>(rowptr, cursor, bsums, N);
    scatter_kernel<<<(E + 255) / 256, 256, 0, stream>>>(Ar, Ac, Av, rnorm, cursor,
                                                        ecol, eval, E);

    int blocks = (N + 63) / 64;  // 16 waves/block, 4 rows/wave
    spmm_gemm_kernel<<<blocks, 1024, 0, stream>>>(x, rowptr, counts, ecol, eval,
                                                  Wp, b, ts, out, N);
}

// Round 3
// 379.123 us; speedup vs baseline: 5.4832x; 1.1931x over previous
//
#include <hip/hip_runtime.h>

constexpr int HD = 128;  // hidden size

__device__ __forceinline__ int rl(int v, int j) {
    return __builtin_amdgcn_readlane(v, j);
}
__device__ __forceinline__ float rlf(int v, int j) {
    return __uint_as_float((unsigned)__builtin_amdgcn_readlane(v, j));
}
__device__ __forceinline__ unsigned f2bf(float f) {  // f32 -> bf16 bits, RNE
    unsigned u = __float_as_uint(f);
    return (u + 0x7fffu + ((u >> 16) & 1u)) >> 16;
}

// ---------------------------------------------------------------------------
// prep: three block-ranges in one launch.
//  [0, PB)        : per-row L1 norm of x; store rnorm; pack xb = bf16(x*rn)
//  [PB, PB+64)    : Wp pair-interleave  Wp[k2*256+2h+j] = W[h][2k2+j]
//  [PB+64, ...)   : histogram of A_rows into counts (4 edges/thread)
// ---------------------------------------------------------------------------
__global__ void prep_kernel(const float* __restrict__ x,
                            unsigned* __restrict__ xb,
                            float* __restrict__ rnorm,
                            const float* __restrict__ W,
                            float* __restrict__ Wp,
                            const int* __restrict__ rows,
                            int* __restrict__ counts,
                            int N, int E, int PB, int packf) {
    int bid = blockIdx.x;
    if (bid < PB) {
        int row = bid * 4 + (threadIdx.x >> 6);
        int lane = threadIdx.x & 63;
        if (row >= N) return;
        float2 v = *((const float2*)(x + (size_t)row * HD) + lane);
        float s = fabsf(v.x) + fabsf(v.y);
#pragma unroll
        for (int m = 1; m < 64; m <<= 1) s += __shfl_xor(s, m, 64);
        float rn = 1.0f / fmaxf(s, 1e-12f);
        if (lane == 0) rnorm[row] = rn;
        if (packf) {
            unsigned lo = f2bf(v.x * rn), hi = f2bf(v.y * rn);
            xb[(size_t)row * 64 + lane] = lo | (hi << 16);
        }
    } else if (bid < PB + 64) {
        int t = (bid - PB) * 256 + threadIdx.x;  // 0..16383
        int k2 = t >> 8, rem = t & 255, h = rem >> 1, j = rem & 1;
        Wp[t] = W[h * HD + 2 * k2 + j];
    } else {
        int base = (bid - PB - 64) * 1024 + threadIdx.x;
#pragma unroll
        for (int i = 0; i < 4; ++i) {
            int e = base + i * 256;
            if (e < E) atomicAdd(&counts[rows[e]], 1);
        }
    }
}

// ---------------------------------------------------------------------------
// CSR scans (exclusive): block-local 1024/blk -> block sums -> add back.
// ---------------------------------------------------------------------------
__global__ void scan1_kernel(const int* __restrict__ counts,
                             int* __restrict__ rowptr,
                             int* __restrict__ bsums, int N) {
    __shared__ int lds[256];
    int t = threadIdx.x;
    int base = blockIdx.x * 1024;
    int v[4];
    int s = 0;
#pragma unroll
    for (int i = 0; i < 4; ++i) {
        int idx = base + t * 4 + i;
        v[i] = (idx < N) ? counts[idx] : 0;
        s += v[i];
    }
    lds[t] = s;
    __syncthreads();
    for (int off = 1; off < 256; off <<= 1) {
        int add = (t >= off) ? lds[t - off] : 0;
        __syncthreads();
        lds[t] += add;
        __syncthreads();
    }
    int run = lds[t] - s;
#pragma unroll
    for (int i = 0; i < 4; ++i) {
        int idx = base + t * 4 + i;
        if (idx < N) rowptr[idx] = run;
        run += v[i];
    }
    if (t == 255) bsums[blockIdx.x] = lds[255];
}

__global__ void scan2_kernel(int* __restrict__ bsums, int nb) {
    __shared__ int lds[256];
    int t = threadIdx.x;
    int v[4];
    int s = 0;
#pragma unroll
    for (int i = 0; i < 4; ++i) {
        int idx = t * 4 + i;
        v[i] = (idx < nb) ? bsums[idx] : 0;
        s += v[i];
    }
    lds[t] = s;
    __syncthreads();
    for (int off = 1; off < 256; off <<= 1) {
        int add = (t >= off) ? lds[t - off] : 0;
        __syncthreads();
        lds[t] += add;
        __syncthreads();
    }
    int run = lds[t] - s;
#pragma unroll
    for (int i = 0; i < 4; ++i) {
        int idx = t * 4 + i;
        if (idx < nb) {
            int tmp = v[i];
            bsums[idx] = run;
            run += tmp;
        }
    }
}

__global__ void scan3_kernel(int* __restrict__ rowptr, int* __restrict__ cursor,
                             const int* __restrict__ bsums, int N) {
    int i = blockIdx.x * blockDim.x + threadIdx.x;
    if (i >= N) return;
    int v = rowptr[i] + bsums[i >> 10];
    rowptr[i] = v;
    cursor[i] = v;
}

// ---------------------------------------------------------------------------
// scatter: permute edges into CSR order as int2{col, val_bits}.
// If rnorm != null (f32 fallback path) pre-scale val by rnorm[col].
// 4 edges/thread, vectorized metadata loads.
// ---------------------------------------------------------------------------
__global__ void scatter_kernel(const int* __restrict__ rows,
                               const int* __restrict__ cols,
                               const float* __restrict__ vals,
                               const float* __restrict__ rnorm,
                               int* __restrict__ cursor,
                               int2* __restrict__ epack, int E) {
    int base = blockIdx.x * 1024 + threadIdx.x;
#pragma unroll
    for (int i = 0; i < 4; ++i) {
        int e = base + i * 256;
        if (e >= E) break;
        int r = rows[e], c = cols[e];
        float v = vals[e];
        if (rnorm) v *= rnorm[c];
        int p = atomicAdd(&cursor[r], 1);
        epack[p] = make_int2(c, __float_as_int(v));
    }
}

// ---------------------------------------------------------------------------
// Fused CSR-SpMM + GEMM + epilogue. One wave = 4 rows.
// PACK=1: gather bf16-packed pre-normalized xb (4B/lane/edge).
// PACK=0: gather f32 x (8B/lane/edge), vals pre-scaled by rnorm.
// Metadata preloaded coalesced (int2/lane), broadcast via readlane.
// ---------------------------------------------------------------------------
template <int PACK>
__global__ void __launch_bounds__(1024) spmm_gemm_kernel(
    const float* __restrict__ x, const unsigned* __restrict__ xb,
    const int* __restrict__ rowptr, const int* __restrict__ counts,
    const int2* __restrict__ epack, const float* __restrict__ Wp,
    const float* __restrict__ b, const float* __restrict__ tsp,
    float* __restrict__ out, int N) {
    __shared__ float lds[HD * HD];  // 64 KiB
    {
        const float4* s4 = (const float4*)Wp;
        float4* d4 = (float4*)lds;
        for (int i = threadIdx.x; i < HD * HD / 4; i += blockDim.x) d4[i] = s4[i];
    }
    __syncthreads();

    int lane = threadIdx.x & 63;
    int wid = threadIdx.x >> 6;
    float ts = tsp[0];
    float b0 = b[2 * lane], b1 = b[2 * lane + 1];

    int r0 = (blockIdx.x * 16 + wid) * 4;
    if (r0 >= N) return;  // no barriers below

    float a0[4] = {0.f, 0.f, 0.f, 0.f}, a1[4] = {0.f, 0.f, 0.f, 0.f};
#pragma unroll
    for (int rr = 0; rr < 4; ++rr) {
        int row = r0 + rr;
        if (row >= N) break;
        int beg = rowptr[row], cnt = counts[row];
        float p0 = 0.f, q0 = 0.f, p1 = 0.f, q1 = 0.f;
        for (int jb = 0; jb < cnt; jb += 64) {
            int rem = cnt - jb;
            if (rem > 64) rem = 64;
            int2 meta = make_int2(0, 0);
            if (lane < rem) meta = epack[beg + jb + lane];
            int j = 0;
            for (; j + 4 <= rem; j += 4) {
                int c0 = rl(meta.x, j), c1 = rl(meta.x, j + 1);
                int c2 = rl(meta.x, j + 2), c3 = rl(meta.x, j + 3);
                float s0 = rlf(meta.y, j), s1 = rlf(meta.y, j + 1);
                float s2 = rlf(meta.y, j + 2), s3 = rlf(meta.y, j + 3);
                if (PACK) {
                    unsigned u0 = xb[(size_t)c0 * 64 + lane];
                    unsigned u1 = xb[(size_t)c1 * 64 + lane];
                    unsigned u2 = xb[(size_t)c2 * 64 + lane];
                    unsigned u3 = xb[(size_t)c3 * 64 + lane];
                    p0 = fmaf(__uint_as_float(u0 << 16), s0, p0);
                    q0 = fmaf(__uint_as_float(u0 & 0xffff0000u), s0, q0);
                    p1 = fmaf(__uint_as_float(u1 << 16), s1, p1);
                    q1 = fmaf(__uint_as_float(u1 & 0xffff0000u), s1, q1);
                    p0 = fmaf(__uint_as_float(u2 << 16), s2, p0);
                    q0 = fmaf(__uint_as_float(u2 & 0xffff0000u), s2, q0);
                    p1 = fmaf(__uint_as_float(u3 << 16), s3, p1);
                    q1 = fmaf(__uint_as_float(u3 & 0xffff0000u), s3, q1);
                } else {
                    float2 v0 = *((const float2*)(x + (size_t)c0 * HD) + lane);
                    float2 v1 = *((const float2*)(x + (size_t)c1 * HD) + lane);
                    float2 v2 = *((const float2*)(x + (size_t)c2 * HD) + lane);
                    float2 v3 = *((const float2*)(x + (size_t)c3 * HD) + lane);
                    p0 = fmaf(v0.x, s0, p0);
                    q0 = fmaf(v0.y, s0, q0);
                    p1 = fmaf(v1.x, s1, p1);
                    q1 = fmaf(v1.y, s1, q1);
                    p0 = fmaf(v2.x, s2, p0);
                    q0 = fmaf(v2.y, s2, q0);
                    p1 = fmaf(v3.x, s3, p1);
                    q1 = fmaf(v3.y, s3, q1);
                }
            }
            for (; j < rem; ++j) {
                int c0 = rl(meta.x, j);
                float s0 = rlf(meta.y, j);
                if (PACK) {
                    unsigned u0 = xb[(size_t)c0 * 64 + lane];
                    p0 = fmaf(__uint_as_float(u0 << 16), s0, p0);
                    q0 = fmaf(__uint_as_float(u0 & 0xffff0000u), s0, q0);
                } else {
                    float2 v0 = *((const float2*)(x + (size_t)c0 * HD) + lane);
                    p0 = fmaf(v0.x, s0, p0);
                    q0 = fmaf(v0.y, s0, q0);
                }
            }
        }
        a0[rr] = p0 + p1;
        a1[rr] = q0 + q1;
    }

    // ---- GEMM: g[c] = dot(f, W[c,:]) for c = 2*lane, 2*lane+1 ----
    float g0[4] = {0.f, 0.f, 0.f, 0.f}, g1[4] = {0.f, 0.f, 0.f, 0.f};
#pragma unroll 8
    for (int k2 = 0; k2 < 64; ++k2) {
        float4 w = *((const float4*)(lds + k2 * 256) + lane);
#pragma unroll
        for (int rr = 0; rr < 4; ++rr) {
            float fk0 = __uint_as_float(
                __builtin_amdgcn_readlane(__float_as_uint(a0[rr]), k2));
            float fk1 = __uint_as_float(
                __builtin_amdgcn_readlane(__float_as_uint(a1[rr]), k2));
            g0[rr] = fmaf(fk0, w.x, g0[rr]);
            g0[rr] = fmaf(fk1, w.y, g0[rr]);
            g1[rr] = fmaf(fk0, w.z, g1[rr]);
            g1[rr] = fmaf(fk1, w.w, g1[rr]);
        }
    }

    // ---- epilogue: bias, L1 normalize, relu, residual ----
#pragma unroll
    for (int rr = 0; rr < 4; ++rr) {
        int row = r0 + rr;
        if (row >= N) break;
        float G0 = g0[rr] + b0, G1 = g1[rr] + b1;
        float s = fabsf(G0) + fabsf(G1);
#pragma unroll
        for (int m = 1; m < 64; m <<= 1) s += __shfl_xor(s, m, 64);
        float rn = 1.0f / fmaxf(s, 1e-12f);
        G0 = fmaxf(G0 * rn, 0.f);
        G1 = fmaxf(G1 * rn, 0.f);
        float2 xv = *((const float2*)(x + (size_t)row * HD) + lane);
        float2 o;
        o.x = fmaf(ts, G0, xv.x);
        o.y = fmaf(ts, G1, xv.y);
        *((float2*)(out + (size_t)row * HD) + lane) = o;
    }
}

extern "C" void kernel_launch(void* const* d_in, const int* in_sizes, int n_in,
                              void* d_out, int out_size, void* d_ws,
                              size_t ws_size, hipStream_t stream) {
    const float* x = (const float*)d_in[0];
    const int* Ar = (const int*)d_in[1];
    const int* Ac = (const int*)d_in[2];
    const float* Av = (const float*)d_in[3];
    const float* W = (const float*)d_in[4];
    const float* b = (const float*)d_in[5];
    const float* ts = (const float*)d_in[6];

    int N = in_sizes[0] / HD;
    int E = in_sizes[1];
    float* out = (float*)d_out;

    char* ws = (char*)d_ws;
    size_t o = 0;
    auto take = [&](size_t bytes) {
        void* p = ws + o;
        o += (bytes + 511) & ~(size_t)511;
        return p;
    };
    // small/base allocations first so the f32 fallback fits a small ws
    float* rnorm = (float*)take((size_t)N * 4);
    int* counts = (int*)take((size_t)N * 4);
    int* rowptr = (int*)take((size_t)N * 4);
    int* cursor = (int*)take((size_t)N * 4);
    int nb = (N + 1023) / 1024;
    int* bsums = (int*)take((size_t)nb * 4);
    float* Wp = (float*)take((size_t)HD * HD * 4);
    int2* epack = (int2*)take((size_t)E * 8);
    size_t base_use = o;
    unsigned* xb = (unsigned*)take((size_t)N * 64 * 4);
    int packf = (o <= ws_size) ? 1 : 0;  // bf16-pack path fits?
    (void)base_use;

    hipMemsetAsync(counts, 0, (size_t)N * 4, stream);

    int PB = (N + 3) / 4;
    int HB = (E + 1023) / 1024;
    prep_kernel<<<PB + 64 + HB, 256, 0, stream>>>(x, xb, rnorm, W, Wp, Ar,
                                                  counts, N, E, PB, packf);
    scan1_kernel<<<nb, 256, 0, stream>>>(counts, rowptr, bsums, N);
    scan2_kernel<<<1, 256, 0, stream>>>(bsums, nb);
    scan3_kernel<<<(N + 255) / 256, 256, 0, stream>>>(rowptr, cursor, bsums, N);
    scatter_kernel<<<(E + 1023) / 1024, 256, 0, stream>>>(
        Ar, Ac, Av, packf ? nullptr : rnorm, cursor, epack, E);

    int blocks = (N + 63) / 64;  // 16 waves/block, 4 rows/wave
    if (packf)
        spmm_gemm_kernel<1><<<blocks, 1024, 0, stream>>>(
            x, xb, rowptr, counts, epack, Wp, b, ts, out, N);
    else
        spmm_gemm_kernel<0><<<blocks, 1024, 0, stream>>>(
            x, xb, rowptr, counts, epack, Wp, b, ts, out, N);
}